// Round 13
// baseline (1117530.957 us; speedup 1.0000x reference)
//
#include <hip/hip_runtime.h>
#include <stdint.h>

typedef float    f32x4  __attribute__((ext_vector_type(4)));
typedef short    short8 __attribute__((ext_vector_type(8)));
typedef uint32_t u32x4  __attribute__((ext_vector_type(4)));

__device__ inline uint16_t f2bf(float f){
  uint32_t u = __float_as_uint(f);
  u += 0x7fffu + ((u >> 16) & 1u);   // RNE
  return (uint16_t)(u >> 16);
}

// ---------------- prepack: weights -> per-WG MFMA B-fragment records (unchanged) ----------------
struct PreP {
  const float *Wdh0,*Wzh0,*Wmup0,*Wsgp0,*Wdh1,*Wzh1,*Wih1,*Wmup1,*Wsgp1,*Wout;
  uint32_t* dst;
};

__global__ __launch_bounds__(64) void prepack(PreP P){
  const int rec = blockIdx.x, l = threadIdx.x;
  int role, s, r;
  if (rec < 832){ role = 0; s = rec / 52; r = rec % 52; }
  else          { role = 1; int rr = rec - 832; s = rr / 82; r = rr % 82; }
  const int cl = l & 15, kb = (l >> 4) * 8;
  float v[8];
#pragma unroll
  for (int j = 0; j < 8; ++j) v[j] = 0.f;
  if (role == 0){
    if (r < 48){
      int n = r >> 4, k = r & 15, c = 16*n + cl, kk0 = k*32 + kb;
      if (c < 32){ int col = 32*s + c;
#pragma unroll
        for (int j = 0; j < 8; ++j) v[j] = P.Wdh0[(size_t)(kk0+j)*512 + col];
      } else if (c < 36){ int col = 4*s + (c-32);
#pragma unroll
        for (int j = 0; j < 8; ++j) v[j] = P.Wmup0[(size_t)(kk0+j)*64 + col];
      } else if (c < 40){ int col = 4*s + (c-36);
#pragma unroll
        for (int j = 0; j < 8; ++j) v[j] = P.Wsgp0[(size_t)(kk0+j)*64 + col];
      }
    } else {
      int r2 = r - 48, n = r2 >> 1, k = r2 & 1, col = 32*s + 16*n + cl, kk0 = k*32 + kb;
#pragma unroll
      for (int j = 0; j < 8; ++j) v[j] = P.Wzh0[(size_t)(kk0+j)*512 + col];
    }
  } else {
    if (r < 48){
      int n = r >> 4, k = r & 15, c = 16*n + cl, kk0 = k*32 + kb;
      if (c < 32){ int col = 32*s + c;
#pragma unroll
        for (int j = 0; j < 8; ++j) v[j] = P.Wdh1[(size_t)(kk0+j)*512 + col];
      } else if (c < 34){ int col = 2*s + (c-32);
#pragma unroll
        for (int j = 0; j < 8; ++j) v[j] = P.Wmup1[(size_t)(kk0+j)*32 + col];
      } else if (c < 36){ int col = 2*s + (c-34);
#pragma unroll
        for (int j = 0; j < 8; ++j) v[j] = P.Wsgp1[(size_t)(kk0+j)*32 + col];
      } else if (c < 40){ int col = 4*s + (c-36);
#pragma unroll
        for (int j = 0; j < 8; ++j) v[j] = P.Wout[(size_t)(kk0+j)*64 + col];
      }
    } else if (r < 80){
      int r2 = r - 48, n = r2 >> 4, k = r2 & 15, col = 32*s + 16*n + cl, kk0 = k*32 + kb;
#pragma unroll
      for (int j = 0; j < 8; ++j) v[j] = P.Wih1[(size_t)(kk0+j)*512 + col];
    } else {
      int n = r - 80, col = 32*s + 16*n + cl;
#pragma unroll
      for (int j = 0; j < 8; ++j) v[j] = P.Wzh1[(size_t)(kb+j)*512 + col];
    }
  }
  u32x4 o;
  o.x = (uint32_t)f2bf(v[0]) | ((uint32_t)f2bf(v[1]) << 16);
  o.y = (uint32_t)f2bf(v[2]) | ((uint32_t)f2bf(v[3]) << 16);
  o.z = (uint32_t)f2bf(v[4]) | ((uint32_t)f2bf(v[5]) << 16);
  o.w = (uint32_t)f2bf(v[6]) | ((uint32_t)f2bf(v[7]) << 16);
  ((u32x4*)(P.dst + (size_t)rec * 256))[l] = o;
}

// ---- transport: pure = XCD-local L2 (plain store / sc0 load); impure = device sc1 ----
#define GLD16_BODY(SC) \
  asm volatile("global_load_dwordx4 %0, %4, off " SC "\n\t" \
               "global_load_dwordx4 %1, %4, off offset:1024 " SC "\n\t" \
               "global_load_dwordx4 %2, %4, off offset:2048 " SC "\n\t" \
               "global_load_dwordx4 %3, %4, off offset:3072 " SC \
               : "=v"(a[0]),"=v"(a[1]),"=v"(a[2]),"=v"(a[3]) : "v"(base) : "memory"); \
  asm volatile("global_load_dwordx4 %0, %4, off " SC "\n\t" \
               "global_load_dwordx4 %1, %4, off offset:1024 " SC "\n\t" \
               "global_load_dwordx4 %2, %4, off offset:2048 " SC "\n\t" \
               "global_load_dwordx4 %3, %4, off offset:3072 " SC \
               : "=v"(a[4]),"=v"(a[5]),"=v"(a[6]),"=v"(a[7]) : "v"(base+2048) : "memory"); \
  asm volatile("global_load_dwordx4 %0, %4, off " SC "\n\t" \
               "global_load_dwordx4 %1, %4, off offset:1024 " SC "\n\t" \
               "global_load_dwordx4 %2, %4, off offset:2048 " SC "\n\t" \
               "global_load_dwordx4 %3, %4, off offset:3072 " SC \
               : "=v"(a[8]),"=v"(a[9]),"=v"(a[10]),"=v"(a[11]) : "v"(base+4096) : "memory"); \
  asm volatile("global_load_dwordx4 %0, %4, off " SC "\n\t" \
               "global_load_dwordx4 %1, %4, off offset:1024 " SC "\n\t" \
               "global_load_dwordx4 %2, %4, off offset:2048 " SC "\n\t" \
               "global_load_dwordx4 %3, %4, off offset:3072 " SC \
               : "=v"(a[12]),"=v"(a[13]),"=v"(a[14]),"=v"(a[15]) : "v"(base+6144) : "memory");

__device__ inline void gld16_rec(u32x4 (&a)[16], const short* base, bool pure){
  if (pure){ GLD16_BODY("sc0") } else { GLD16_BODY("sc1") }
}
__device__ inline void st16_m(short* dst, u32x4 v, bool pure){
  if (pure) asm volatile("global_store_dwordx4 %0, %1, off"     :: "v"(dst), "v"(v) : "memory");
  else      asm volatile("global_store_dwordx4 %0, %1, off sc1" :: "v"(dst), "v"(v) : "memory");
}
__device__ inline void flag_m(uint32_t* dst, bool pure){
  uint32_t v = 0xFFFFFFFFu;
  if (pure) asm volatile("global_store_dword %0, %1, off"     :: "v"(dst), "v"(v) : "memory");
  else      asm volatile("global_store_dword %0, %1, off sc1" :: "v"(dst), "v"(v) : "memory");
}
__device__ inline void vm_drain(){
  asm volatile("s_waitcnt vmcnt(0)" ::: "memory");
}
#define LINE64_BODY(SC, A0,A1,A2,A3, Q) \
  asm volatile("global_load_dwordx4 %0, %4, off " SC "\n\t" \
               "global_load_dwordx4 %1, %4, off offset:16 " SC "\n\t" \
               "global_load_dwordx4 %2, %4, off offset:32 " SC "\n\t" \
               "global_load_dwordx4 %3, %4, off offset:48 " SC \
               : "=v"(A0),"=v"(A1),"=v"(A2),"=v"(A3) : "v"(Q) : "memory");

__device__ inline bool line64(const uint32_t* q, bool pure){
  u32x4 a0,a1,a2,a3;
  if (pure){ LINE64_BODY("sc0", a0,a1,a2,a3, q) } else { LINE64_BODY("sc1", a0,a1,a2,a3, q) }
  vm_drain();
  u32x4 m = (a0 & a1) & (a2 & a3);
  return (m.x & m.y & m.z & m.w) == 0xFFFFFFFFu;
}
__device__ inline void line64x2(const uint32_t* qa, const uint32_t* qb, bool& oa, bool& ob, bool pure){
  u32x4 a0,a1,a2,a3,b0,b1,b2,b3;
  if (pure){ LINE64_BODY("sc0", a0,a1,a2,a3, qa) LINE64_BODY("sc0", b0,b1,b2,b3, qb) }
  else     { LINE64_BODY("sc1", a0,a1,a2,a3, qa) LINE64_BODY("sc1", b0,b1,b2,b3, qb) }
  vm_drain();
  u32x4 ma = (a0 & a1) & (a2 & a3);
  u32x4 mb = (b0 & b1) & (b2 & b3);
  oa = (ma.x & ma.y & ma.z & ma.w) == 0xFFFFFFFFu;
  ob = (mb.x & mb.y & mb.z & mb.w) == 0xFFFFFFFFu;
}

// stats pipeline (r11): plain clamped loads, compiler-managed hazards
#define ISSUE(NI, NE, SH, CWv, tt) do { \
  _Pragma("unroll") \
  for (int i = 0; i < (NI); ++i){ \
    int idx = (tid - 64) + 128*i; \
    int cidx = idx < (NE) ? idx : (NE)-1; \
    int rr = cidx >> (SH), cc = cidx & ((CWv)-1); \
    size_t sidx = ((size_t)(16*g + rr) * 2048 + (size_t)(tt)) * (CWv) + cc; \
    ra[i] = AM[sidx]; rsg[i] = AS[sidx]; rep[i] = EP[sidx]; \
  } \
} while(0)

#define PROCESS(NI, NE, SH, CWv, tt) do { \
  const int par2 = (tt) % 3; \
  _Pragma("unroll") \
  for (int i = 0; i < (NI); ++i){ \
    int idx = (tid - 64) + 128*i; \
    if (idx < (NE)){ \
      int rr = idx >> (SH), cc = idx & ((CWv)-1); \
      float mq = tanhf(ra[i]), tq = tanhf(rsg[i]); \
      muqS[par2*1024 + rr*64 + cc] = mq; \
      tqS [par2*1024 + rr*64 + cc] = tq; \
      zbS [par2*1152 + rr*72 + cc] = (short)f2bf(fmaf(__expf(tq), rep[i], mq)); \
    } \
  } \
} while(0)

// ---------------- scan: 8 XCD-local groups x 16 rows; claim-based placement ----------------
struct ScanP {
  const short* wrec;
  short* pub;                          // [layer2][ring4][group8][16 recs x 1KB]
  uint32_t *flgA, *flgB;               // [group8][t2048][16 u32]
  int* claim;                          // [8] cnt + [8] done
  const float *bh0,*bmup0,*bsgp0,*bh1,*bmup1,*bsgp1,*bout;
  const float *Am0,*As0,*E0,*Am1,*As1,*E1;
  float *out, *klpart;
};

__global__ __launch_bounds__(192, 1) void pvrnn_scan(ScanP P){
  extern __shared__ char smem[];
  short* ldsW  = (short*)smem;                   // up to 82 recs * 1KB   [0, 83968)
  short* zbS   = (short*)(smem + 83968);         // [3][16][72] bf16      -> 90880
  float* muqS  = (float*)(smem + 90880);         // [3][16][64] f32       -> 103168
  float* tqS   = (float*)(smem + 103168);        // [3][16][64] f32       -> 115456
  short* dtile = (short*)(smem + 115456);        // [16][40] bf16         -> 116736
  float* mupT  = (float*)(smem + 116736);        // [16][4]               -> 116992
  float* tpT   = (float*)(smem + 116992);        // [16][4]               -> 117248
  float* xT    = (float*)(smem + 117248);        // [16][4]               -> 117504
  int*   slotS = (int*)  (smem + 117504);        // [4]                   -> 117568

  const int tid = threadIdx.x;
  const int l = tid & 63, w = tid >> 6;           // waves 0,1 recurrent; 2 heads
  const int c = l & 15, kb8 = (l >> 4) * 8;

  // ---- phase 0: runtime XCD claim (correct on ANY placement) ----
  if (tid == 0){
    uint32_t xcc;
    asm volatile("s_getreg_b32 %0, hwreg(HW_REG_XCC_ID)" : "=s"(xcc));
    xcc &= 7;
    int rank = __hip_atomic_fetch_add(&P.claim[xcc], 1, __ATOMIC_RELAXED, __HIP_MEMORY_SCOPE_AGENT);
    __hip_atomic_fetch_add(&P.claim[8], 1, __ATOMIC_RELEASE, __HIP_MEMORY_SCOPE_AGENT);
    int it = 0; bool cdead = false;
    while (__hip_atomic_load(&P.claim[8], __ATOMIC_ACQUIRE, __HIP_MEMORY_SCOPE_AGENT) < 256){
      __builtin_amdgcn_s_sleep(2);
      if (++it > 3000000){ cdead = true; break; }
    }
    int slot, pure;
    if (cdead){ slot = blockIdx.x; pure = 0; }
    else {
      int cnt[8];
#pragma unroll
      for (int x = 0; x < 8; ++x)
        cnt[x] = __hip_atomic_load(&P.claim[x], __ATOMIC_RELAXED, __HIP_MEMORY_SCOPE_AGENT);
      if (rank < 32) slot = (int)xcc*32 + rank;
      else {
        int o = rank - 32;
        for (int x = 0; x < (int)xcc; ++x) o += cnt[x] > 32 ? cnt[x] - 32 : 0;
        slot = -1;
        for (int x = 0; x < 8; ++x){
          int d = 32 - cnt[x]; if (d < 0) d = 0;
          if (o < d){ slot = x*32 + cnt[x] + o; break; }
          o -= d;
        }
        if (slot < 0) slot = blockIdx.x;          // paranoia (shouldn't happen)
      }
      pure = (cnt[slot >> 5] >= 32) ? 1 : 0;
    }
    slotS[0] = slot; slotS[1] = pure; slotS[2] = cdead ? 1 : 0;
  }
  __syncthreads();
  const int  slot = slotS[0];
  const bool pure = slotS[1] != 0;
  bool dead = slotS[2] != 0;
  const int g    = slot >> 5;
  const int role = (slot >> 4) & 1;
  const int s    = slot & 15;
  const int wid  = slot;

  { // weights -> LDS
    const u32x4* src = (const u32x4*)(P.wrec + (size_t)(role ? (832 + s*82) : (s*52)) * 512);
    const int n16 = (role ? 82 : 52) * 64;
    for (int i = tid; i < n16; i += 192) ((u32x4*)ldsW)[i] = src[i];
  }
  float bias_rec = 0.f, bias_head = 0.f;
  if (w < 2){
    bias_rec = role ? P.bh1[32*s + 16*w + c] : P.bh0[32*s + 16*w + c];
  } else {
    if (!role){
      if (c < 4)      bias_head = P.bmup0[4*s + c];
      else if (c < 8) bias_head = P.bsgp0[4*s + c - 4];
    } else {
      if (c < 2)      bias_head = P.bmup1[2*s + c];
      else if (c < 4) bias_head = P.bsgp1[2*s + c - 2];
      else if (c < 8) bias_head = P.bout [4*s + c - 4];
    }
  }
  const float* AM = role ? P.Am1 : P.Am0;
  const float* AS = role ? P.As1 : P.As0;
  const float* EP = role ? P.E1  : P.E0;
  const int CW = role ? 32 : 64;
  const int sh = role ? 5 : 6;

  float ra[8], rsg[8], rep[8];

  if (tid >= 64){   // slot 0 stats direct, then issue loads for t=1
    const int NE = 16 << sh;
    for (int idx = tid - 64; idx < NE; idx += 128){
      int rr = idx >> sh, cc = idx & (CW - 1);
      size_t sidx = ((size_t)(16*g + rr) * 2048 + 0) * CW + cc;
      float mq = tanhf(AM[sidx]);
      float tq = tanhf(AS[sidx]);
      muqS[rr*64 + cc] = mq;
      tqS [rr*64 + cc] = tq;
      zbS [rr*72 + cc] = (short)f2bf(fmaf(__expf(tq), EP[sidx], mq));
    }
    if (!role) ISSUE(8, 1024, 6, 64, 1); else ISSUE(4, 512, 5, 32, 1);
  }
  __syncthreads();

  float h[4] = {0.f,0.f,0.f,0.f};
  float klacc = 0.f;
  short* pubL0 = P.pub;
  short* pubL1 = P.pub + 4*8*8192;
  const short* pubA = role ? pubL1 : pubL0;
  short* pubW = role ? pubL1 : pubL0;
  uint32_t* flgSelf = role ? P.flgB : P.flgA;
  const float leak = role ? 0.875f : 0.5f, gain = role ? 0.125f : 0.5f;

  for (int t = 0; t < 2048; ++t){
    // ---- poll (tid0) overlapped with stats-process (waves 1,2) ----
    if (tid == 0){
      const uint32_t *q1 = nullptr, *q2 = nullptr;
      if (!role){
        if (t >= 4) q1 = P.flgB + ((size_t)g*2048 + (t-4))*16;
        if (t >= 1) q2 = P.flgA + ((size_t)g*2048 + (t-1))*16;
      } else {
        q1 = P.flgA + ((size_t)g*2048 + t)*16;
        if (t >= 1) q2 = P.flgB + ((size_t)g*2048 + (t-1))*16;
      }
      int it = 0;
      while (!dead && (q1 || q2)){
        const uint32_t* A  = q1 ? q1 : q2;
        const uint32_t* B2 = q2 ? q2 : q1;
        bool okA, okB;
        line64x2(A, B2, okA, okB, pure);
        if (q1 && okA) q1 = nullptr;
        if (q2 && okB) q2 = nullptr;
        if (!q1 && !q2) break;
        __builtin_amdgcn_s_sleep(1);
        if (++it > 3000000) dead = true;
      }
    } else if (tid >= 64 && t + 1 < 2048){
      if (!role) PROCESS(8, 1024, 6, 64, t+1); else PROCESS(4, 512, 5, 32, t+1);
    }
    __syncthreads();                              // B1

    const int par = t % 3;
    const short* baseS = pubA + (size_t)(((t-1)&3)*8 + g)*8192 + l*8;
    u32x4 af[16], ag[16];
    gld16_rec(af, baseS, pure);
    if (role && w < 2){
      const short* baseO = pubL0 + (size_t)((t&3)*8 + g)*8192 + l*8;
      gld16_rec(ag, baseO, pure);
    }
    const bool issued = (tid >= 64) && (t + 2 < 2048);
    if (issued){
      if (!role) ISSUE(8, 1024, 6, 64, t+2); else ISSUE(4, 512, 5, 32, t+2);
    }
    if (!issued)      vm_drain();
    else if (!role)   asm volatile("s_waitcnt vmcnt(24)" ::: "memory");
    else              asm volatile("s_waitcnt vmcnt(12)" ::: "memory");
    __builtin_amdgcn_sched_barrier(0);

    f32x4 av[4] = {{0.f,0.f,0.f,0.f},{0.f,0.f,0.f,0.f},{0.f,0.f,0.f,0.f},{0.f,0.f,0.f,0.f}};
    if (w < 2){
#pragma unroll
      for (int k = 0; k < 16; ++k){
        short8 b = *(const short8*)(ldsW + (w*16 + k)*512 + l*8);
        av[k&3] = __builtin_amdgcn_mfma_f32_16x16x32_bf16(*(const short8*)&af[k], b, av[k&3], 0,0,0);
      }
      if (role){
#pragma unroll
        for (int k = 0; k < 16; ++k){
          short8 b = *(const short8*)(ldsW + (48 + w*16 + k)*512 + l*8);
          av[k&3] = __builtin_amdgcn_mfma_f32_16x16x32_bf16(*(const short8*)&ag[k], b, av[k&3], 0,0,0);
        }
        short8 az = *(const short8*)(zbS + par*1152 + c*72 + kb8);
        short8 bz = *(const short8*)(ldsW + (80 + w)*512 + l*8);
        av[0] = __builtin_amdgcn_mfma_f32_16x16x32_bf16(az, bz, av[0], 0,0,0);
      } else {
        short8 az0 = *(const short8*)(zbS + par*1152 + c*72 + kb8);
        short8 az1 = *(const short8*)(zbS + par*1152 + c*72 + 32 + kb8);
        short8 bz0 = *(const short8*)(ldsW + (48 + w*2    )*512 + l*8);
        short8 bz1 = *(const short8*)(ldsW + (48 + w*2 + 1)*512 + l*8);
        av[0] = __builtin_amdgcn_mfma_f32_16x16x32_bf16(az0, bz0, av[0], 0,0,0);
        av[1] = __builtin_amdgcn_mfma_f32_16x16x32_bf16(az1, bz1, av[1], 0,0,0);
      }
    } else {
#pragma unroll
      for (int k = 0; k < 16; ++k){
        short8 b = *(const short8*)(ldsW + (32 + k)*512 + l*8);
        av[k&3] = __builtin_amdgcn_mfma_f32_16x16x32_bf16(*(const short8*)&af[k], b, av[k&3], 0,0,0);
      }
    }
    f32x4 acc = (av[0] + av[1]) + (av[2] + av[3]);

    // ---- epilogue ----
    if (w < 2){
#pragma unroll
      for (int j = 0; j < 4; ++j){
        float pre = acc[j] + bias_rec;
        h[j] = leak*h[j] + gain*pre;
        int row = (l>>4)*4 + j;
        dtile[row*40 + 16*w + c] = (short)f2bf(tanhf(h[j]));
      }
    } else {
#pragma unroll
      for (int j = 0; j < 4; ++j){
        float pre = acc[j] + bias_head;
        int row = (l>>4)*4 + j;
        if (!role){
          if (c < 4)      mupT[row*4 + c]     = tanhf(pre);
          else if (c < 8) tpT [row*4 + c - 4] = tanhf(pre);
        } else {
          if (c < 2)      mupT[row*4 + c]     = tanhf(pre);
          else if (c < 4) tpT [row*4 + c - 2] = tanhf(pre);
          else if (c < 8) xT  [row*4 + c - 4] = 1.f/(1.f + __expf(-pre));
        }
      }
    }
    __syncthreads();                              // B2

    if (w == 0){                                  // publish record s (one 16B store/lane) + flag
      u32x4 v = *(const u32x4*)(dtile + (l&15)*40 + (l>>4)*8);
      st16_m(pubW + (size_t)((t&3)*8 + g)*8192 + s*512 + l*8, v, pure);
      vm_drain();                                 // data committed before flag
      if (l == 0)
        flag_m(flgSelf + ((size_t)g*2048 + t)*16 + s, pure);
    } else if (w == 2 && l < 16){
      if (role && t >= 1)
        *(float4*)(P.out + ((size_t)(16*g + l)*2048 + (t-1))*64 + 4*s)
          = *(const float4*)(xT + l*4);
      const int CC = role ? 2 : 4;
#pragma unroll
      for (int cc = 0; cc < 4; ++cc){
        if (cc < CC){
          float mp = mupT[l*4 + cc], tp = tpT[l*4 + cc];
          int zc = role ? (2*s + cc) : (4*s + cc);
          float mq = muqS[par*1024 + l*64 + zc];
          float tq = tqS [par*1024 + l*64 + zc];
          float dm = mq - mp;
          klacc += tp - tq + (__expf(2.f*tq) + dm*dm)*0.5f*__expf(-2.f*tp) - 0.5f;
        }
      }
    }
  }

  if (role){                                      // final x(2047)
    if (tid == 0){
      const uint32_t* q = P.flgB + ((size_t)g*2048 + 2047)*16;
      int it = 0;
      while (!dead && !line64(q, pure)){
        __builtin_amdgcn_s_sleep(1);
        if (++it > 3000000) dead = true;
      }
    }
    __syncthreads();
    if (w == 2){
      const short* baseS = pubL1 + (size_t)(3*8 + g)*8192 + l*8;   // ring 2047&3 = 3
      u32x4 af[16];
      gld16_rec(af, baseS, pure);
      vm_drain();
      __builtin_amdgcn_sched_barrier(0);
      f32x4 av[4] = {{0.f,0.f,0.f,0.f},{0.f,0.f,0.f,0.f},{0.f,0.f,0.f,0.f},{0.f,0.f,0.f,0.f}};
#pragma unroll
      for (int k = 0; k < 16; ++k){
        short8 b = *(const short8*)(ldsW + (32 + k)*512 + l*8);
        av[k&3] = __builtin_amdgcn_mfma_f32_16x16x32_bf16(*(const short8*)&af[k], b, av[k&3], 0,0,0);
      }
      f32x4 acc = (av[0] + av[1]) + (av[2] + av[3]);
#pragma unroll
      for (int j = 0; j < 4; ++j){
        if (c >= 4 && c < 8){
          int row = (l>>4)*4 + j;
          xT[row*4 + c - 4] = 1.f/(1.f + __expf(-(acc[j] + bias_head)));
        }
      }
    }
    __syncthreads();
    if (w == 2 && l < 16)
      *(float4*)(P.out + ((size_t)(16*g + l)*2048 + 2047)*64 + 4*s)
        = *(const float4*)(xT + l*4);
  }

  if (w == 2){
    float v = klacc;
#pragma unroll
    for (int off = 32; off; off >>= 1) v += __shfl_down(v, off);
    if (l == 0) P.klpart[wid] = v;
  }
}

__global__ void kl_finalize(const float* __restrict__ klpart, float* __restrict__ out){
  if (blockIdx.x == 0 && threadIdx.x == 0){
    float k0 = 0.f, k1 = 0.f;
    for (int i = 0; i < 256; ++i){
      if ((i >> 4) & 1) k1 += klpart[i]; else k0 += klpart[i];
    }
    float kl = (k0 + k1) * (1.0f/128.0f);
    out[16777216] = kl;
    out[16777217] = 0.001f * kl;
  }
}

extern "C" void kernel_launch(void* const* d_in, const int* in_sizes, int n_in,
                              void* d_out, int out_size, void* d_ws, size_t ws_size,
                              hipStream_t stream){
  (void)in_sizes; (void)n_in; (void)out_size;
  const float* Wdh0  = (const float*)d_in[0];
  const float* Wzh0  = (const float*)d_in[1];
  const float* bh0   = (const float*)d_in[2];
  const float* Wmup0 = (const float*)d_in[3];
  const float* bmup0 = (const float*)d_in[4];
  const float* Wsgp0 = (const float*)d_in[5];
  const float* bsgp0 = (const float*)d_in[6];
  const float* Amu0  = (const float*)d_in[7];
  const float* Asg0  = (const float*)d_in[8];
  const float* Eps0  = (const float*)d_in[9];
  const float* Wdh1  = (const float*)d_in[10];
  const float* Wzh1  = (const float*)d_in[11];
  const float* Wih1  = (const float*)d_in[12];
  const float* bh1   = (const float*)d_in[13];
  const float* Wmup1 = (const float*)d_in[14];
  const float* bmup1 = (const float*)d_in[15];
  const float* Wsgp1 = (const float*)d_in[16];
  const float* bsgp1 = (const float*)d_in[17];
  const float* Amu1  = (const float*)d_in[18];
  const float* Asg1  = (const float*)d_in[19];
  const float* Eps1  = (const float*)d_in[20];
  const float* Wout  = (const float*)d_in[21];
  const float* bout  = (const float*)d_in[22];

  const size_t oW    = 0;                        // 2144 recs * 1KB = 2,195,456
  const size_t oPub  = 2195456;                  // 2*4*8*16KB = 1MB
  const size_t oFlgA = oPub  + 1048576;          // 8g*2048*64B = 1MB
  const size_t oFlgB = oFlgA + 1048576;          // 1MB
  const size_t oClm  = oFlgB + 1048576;          // 64B
  const size_t oKL   = oClm + 64;                // 1KB
  const size_t total = oKL + 1024;
  if (ws_size < total) return;
  char* ws = (char*)d_ws;

  (void)hipMemsetAsync(ws + oPub, 0, total - oPub, stream);  // zero pub + flags + claim + klpart

  PreP pp;
  pp.Wdh0 = Wdh0; pp.Wzh0 = Wzh0; pp.Wmup0 = Wmup0; pp.Wsgp0 = Wsgp0;
  pp.Wdh1 = Wdh1; pp.Wzh1 = Wzh1; pp.Wih1 = Wih1; pp.Wmup1 = Wmup1;
  pp.Wsgp1 = Wsgp1; pp.Wout = Wout; pp.dst = (uint32_t*)(ws + oW);
  prepack<<<dim3(2144), dim3(64), 0, stream>>>(pp);

  ScanP sp;
  sp.wrec = (const short*)(ws + oW);
  sp.pub  = (short*)(ws + oPub);
  sp.flgA = (uint32_t*)(ws + oFlgA);
  sp.flgB = (uint32_t*)(ws + oFlgB);
  sp.claim = (int*)(ws + oClm);
  sp.bh0 = bh0; sp.bmup0 = bmup0; sp.bsgp0 = bsgp0;
  sp.bh1 = bh1; sp.bmup1 = bmup1; sp.bsgp1 = bsgp1; sp.bout = bout;
  sp.Am0 = Amu0; sp.As0 = Asg0; sp.E0 = Eps0;
  sp.Am1 = Amu1; sp.As1 = Asg1; sp.E1 = Eps1;
  sp.out = (float*)d_out;
  sp.klpart = (float*)(ws + oKL);

  const unsigned SMEM = 117568u;
  (void)hipFuncSetAttribute((const void*)pvrnn_scan,
                            hipFuncAttributeMaxDynamicSharedMemorySize, 131072);
  void* args[] = { &sp };
  if (hipLaunchCooperativeKernel((void*)pvrnn_scan, dim3(256), dim3(192),
                                 args, SMEM, stream) != hipSuccess){
    pvrnn_scan<<<dim3(256), dim3(192), SMEM, stream>>>(sp);
  }
  kl_finalize<<<1, 1, 0, stream>>>((const float*)(ws + oKL), (float*)d_out);
}